// Round 8
// baseline (124.399 us; speedup 1.0000x reference)
//
#include <hip/hip_runtime.h>
#include <cmath>

// Kalman_Smooth_Gradient: B=4096 seqs, T=128 steps, 6-state EKF + RTS + loss.
// Round 23: backward is dependency-latency-bound (r19: +33 indep insts ->
// +1.2cyc each; r20: -15 dep insts -> no gain). The RTS recursion is AFFINE
// given forward history: s_s(n) = A_n + G_n s_s(n+1); P_s(n) = C_n +
// G_n P_s(n+1) G_n^T, with A,C,G from ring data (available iters ahead).
// TWO-STEP FUSION: precompute H=G_b G_a, B=A_b+G_b A_a, C2=C_b+G_b C_a G_b^T
// off-critical-path; serial chain per PAIR = one matvec + one congruence ->
// half the dependency depth. Outputs per step only need s_s(n).x, P_s(n)._00.
// Also: quadratic loss term a*e^2 is filter-separable -> accumulated in-kernel
// (one atomic per wave); store only 'a' (float) -> WRITE halves, reduce reads
// 6.3MB. Forward loop unchanged (r22, proven).

namespace {

constexpr int B = 4096;
constexpr int T = 128;
constexpr int NT = B * 3;           // 12288 filter chains
constexpr int CPB = 64;             // chains (= threads) per block, one wave
constexpr int NBLK = NT / CPB;      // 192 blocks
constexpr int RBLK = 256;           // reduce kernel blocks
constexpr int RTH = 256;            // reduce kernel threads

constexpr float DTc     = 1.0f / 120.0f;
constexpr float TWO_PIc = 6.28318530717958647692f;
constexpr float PI_1_5  = 4.71238898038468985769f;
constexpr float INV_2PI = 0.15915494309189533577f;

__device__ __forceinline__ float frcp(float x) { return __builtin_amdgcn_rcpf(x); }

__device__ __forceinline__ float fast_tanh(float x) {
  float e = __expf(2.0f * x);
  return 1.0f - 2.0f * frcp(e + 1.0f);
}
__device__ __forceinline__ float sigmoidf(float x) {
  return frcp(1.0f + __expf(-x));
}

// ---------------------------------------------------------------------------
// z transpose: z[s][t][f] -> zt[f][t][s]. Block = 256 thr, tile = 64 seqs x
// 32 t x 3 f (24960 B LDS, stride-65 cols). Grid 256 blocks. Block 0 zeroes
// the output scalar (replaces memset dispatch).
// ---------------------------------------------------------------------------
__global__ __launch_bounds__(256) void ztrans_kernel(
    const float* __restrict__ z, float* __restrict__ zt,
    float* __restrict__ out) {
  __shared__ float tile[96 * 65];
  const int tid = threadIdx.x;
  if (blockIdx.x == 0 && tid == 0) out[0] = 0.0f;
  const int bs = blockIdx.x & 63;        // seq-chunk 0..63
  const int bt = blockIdx.x >> 6;        // t-chunk 0..3
  const int s0 = bs * 64, t0 = bt * 32;

  const float* __restrict__ zbase = z + (size_t)s0 * 384 + t0 * 3;
#pragma unroll
  for (int k = 0; k < 6; k++) {
    const int idx = tid + k * 256;       // 0..1535
    const int sl = idx / 24;             // seq-local 0..63
    const int c4 = idx - sl * 24;        // float4 col 0..23
    const float4 v4 = *(const float4*)(zbase + (size_t)sl * 384 + c4 * 4);
    tile[(c4 * 4 + 0) * 65 + sl] = v4.x;
    tile[(c4 * 4 + 1) * 65 + sl] = v4.y;
    tile[(c4 * 4 + 2) * 65 + sl] = v4.z;
    tile[(c4 * 4 + 3) * 65 + sl] = v4.w;
  }
  __syncthreads();
#pragma unroll
  for (int k = 0; k < 24; k++) {
    const int idx = tid + k * 256;       // 0..6143
    const int r  = idx >> 6;             // 0..95
    const int sl = idx & 63;
    const int fc = r >> 5;               // 0..2
    const int tl = r & 31;
    zt[((size_t)fc * T + t0 + tl) * B + s0 + sl] = tile[(tl * 3 + fc) * 65 + sl];
  }
}

// ---------------------------------------------------------------------------
// Main filter kernel. Forward = r22 core (proven). Backward = two-step fused
// affine recursion. av: [f][T][B] float 'a' values (n = 2..T-1); quadratic
// terms accumulated in-kernel -> one atomicAdd per wave.
// ---------------------------------------------------------------------------
__global__ __launch_bounds__(CPB, 1) void filt_kernel(
    const float* __restrict__ params, const float* __restrict__ covp,
    const float* __restrict__ init_states, const float* __restrict__ zt,
    float* __restrict__ av, float* __restrict__ out) {
  const int lane = threadIdx.x;            // 0..63
  const int blk  = blockIdx.x;             // 0..191
  const int f    = blk >> 6;               // filter 0=x,1=y,2=theta (uniform)
  const int seq  = ((blk & 63) << 6) + lane;

  __shared__ float4 h4s[127 * CPB];        // 130048 B, slot [t*64 + lane]
  __shared__ float  p11s[T * CPB];         //  32768 B, slot [t*64 + lane]

  // ---- shared scalars ----
  const float friction = (fast_tanh(params[0]) + 1.0f) * 0.01f;
  const float damping  = (fast_tanh(params[1]) + 1.0f) * 0.01f;
  float cp[7];
#pragma unroll
  for (int i = 0; i < 7; i++) cp[i] = sigmoidf(covp[i]);
  const float dcoef = 1.0f - DTc * damping;
  const bool isTH = (f == 2);              // wave-uniform branch
  const float q0 = isTH ? cp[5] : cp[3];
  const float q1 = isTH ? cp[6] : cp[4];
  const float r  = cp[f];

  // ---- init ----
  const int pidx = (f == 0) ? 0 : (f == 1) ? 1 : 4;
  const int vidx = (f == 0) ? 2 : (f == 1) ? 3 : 5;
  float p = init_states[seq * 6 + pidx];
  float v = init_states[seq * 6 + vidx];
  float P00 = 0.01f, P01 = 0.0f, P11 = 0.01f;

  const float* __restrict__ ztf = zt + (size_t)f * T * B + seq;

  // =========================== forward ===========================
  float zr[8];
#pragma unroll
  for (int k = 0; k < 8; k++) zr[k] = ztf[(size_t)k * B];
  float zlast = 0.0f;

#define FWD_BODY(t, REFILL)                                                  \
  {                                                                          \
    const float zc = zr[(t) & 7];                                            \
    if (REFILL) zr[(t) & 7] = ztf[(size_t)((t) + 8) * B];                    \
    float g, tv;                                                             \
    if (!isTH) {                                                             \
      const float th = fast_tanh(100.0f * v);                                \
      tv = v - DTc * (damping * v + friction * th);                          \
      g = 1.0f - DTc * (damping + 100.0f * friction * (1.0f - th * th));     \
    } else {                                                                 \
      tv = dcoef * v;                                                        \
      g = dcoef;                                                             \
    }                                                                        \
    const float tp = p + DTc * v;                                            \
    const float u = P01 + DTc * P11;                                         \
    const float Pp00 = P00 + DTc * P01 + DTc * u + q0;                       \
    const float Pp01 = g * u;                                                \
    const float Pp11 = g * (g * P11) + q1;                                   \
    const float iS = frcp(Pp00 + r);                                         \
    const float K0 = Pp00 * iS;                                              \
    const float K1 = Pp01 * iS;                                              \
    float e = zc - tp;                                                       \
    if (isTH) e = e - TWO_PIc * rintf(e * INV_2PI);                          \
    p = tp + K0 * e;                                                         \
    v = tv + K1 * e;                                                         \
    const float om = 1.0f - K0;                                              \
    P00 = om * Pp00;                                                         \
    P01 = om * Pp01;                                                         \
    P11 = Pp11 - K1 * Pp01;                                                  \
    if ((t) < 127) h4s[(t) * CPB + lane] = make_float4(p, v, P00, P01);      \
    p11s[(t) * CPB + lane] = P11;                                            \
    if ((t) == 127) zlast = zc;                                              \
  }

#pragma unroll 8
  for (int t = 0; t < 120; t++) FWD_BODY(t, true)
#pragma unroll
  for (int t = 120; t < 128; t++) FWD_BODY(t, false)
#undef FWD_BODY

  float qsum = 0.0f;

  // ---- terminal loss term n = T-1 (smoothed == filtered) ----
  {
    float e = zlast - p;
    if (isTH) {
      if (e >  PI_1_5) e -= TWO_PIc;
      if (e < -PI_1_5) e += TWO_PIc;
    }
    const float a = P00 + r;
    av[((size_t)f * T + (T - 1)) * B + seq] = a;
    qsum += a * e * e;
  }

  // =========================== backward ===========================
  float sp_ = p, sv_ = v, Ps00 = P00, Ps01 = P01, Ps11 = P11;

  float4 h4r[4];
  float  p11r[4];
  float  zrb[8];
#pragma unroll
  for (int k = 0; k < 4; k++) {
    h4r[k]  = h4s[(126 - k) * CPB + lane];
    p11r[k] = p11s[(126 - k) * CPB + lane];
  }
#pragma unroll
  for (int k = 0; k < 8; k++) zrb[k] = ztf[(size_t)(126 - k) * B];

// G/A/C builder from filtered state at step n (ring data only).
#define BUILD_G(H4, F11, G00,G01,G10,G11, TP,TV, PP00,PP01,PP11)             \
    float G00, G01, G10, G11, TP, TV, PP00, PP01, PP11;                      \
    {                                                                        \
      const float fp_ = (H4).x, fv_ = (H4).y, f00_ = (H4).z, f01_ = (H4).w;  \
      float g_;                                                              \
      if (!isTH) {                                                           \
        const float th_ = fast_tanh(100.0f * fv_);                           \
        TV = fv_ - DTc * (damping * fv_ + friction * th_);                   \
        g_ = 1.0f - DTc * (damping + 100.0f * friction * (1.0f - th_ * th_));\
      } else {                                                               \
        TV = dcoef * fv_;                                                    \
        g_ = dcoef;                                                          \
      }                                                                      \
      TP = fp_ + DTc * fv_;                                                  \
      const float u_ = f01_ + DTc * (F11);                                   \
      PP00 = f00_ + DTc * f01_ + DTc * u_ + q0;                              \
      PP01 = g_ * u_;                                                        \
      PP11 = g_ * (g_ * (F11)) + q1;                                         \
      const float idet_ = frcp(PP00 * PP11 - PP01 * PP01);                   \
      const float W01_ = DTc * f00_ + g_ * f01_;                             \
      const float W11_ = DTc * f01_ + g_ * (F11);                            \
      G00 = (f00_ * PP11 - W01_ * PP01) * idet_;                             \
      G01 = (W01_ * PP00 - f00_ * PP01) * idet_;                             \
      G10 = (f01_ * PP11 - W11_ * PP01) * idet_;                             \
      G11 = (W11_ * PP00 - f01_ * PP01) * idet_;                             \
    }

// symmetric congruence: O = G P G^T (P, O symmetric 2x2)
#define CONG3(G00,G01,G10,G11, P00_,P01_,P11_, O00,O01,O11)                  \
    {                                                                        \
      const float t0_ = (G00)*(P00_) + (G01)*(P01_);                         \
      const float t1_ = (G00)*(P01_) + (G01)*(P11_);                         \
      const float t2_ = (G10)*(P00_) + (G11)*(P01_);                         \
      const float t3_ = (G10)*(P01_) + (G11)*(P11_);                         \
      O00 = t0_*(G00) + t1_*(G01);                                           \
      O01 = t0_*(G10) + t1_*(G11);                                           \
      O11 = t2_*(G10) + t3_*(G11);                                           \
    }

// Fused pair: steps nA = 126-I0 and nB = nA-1.
#define PAIR_BODY(I0, RH4A, RH4B, RZA, RZB)                                  \
  {                                                                          \
    const int iA = (I0), iB = (I0) + 1;                                      \
    const int nA = 126 - iA, nB = 126 - iB;                                  \
    const float4 h4a = h4r[iA & 3]; const float f11a = p11r[iA & 3];         \
    const float4 h4b = h4r[iB & 3]; const float f11b = p11r[iB & 3];         \
    const float za = zrb[iA & 7], zb = zrb[iB & 7];                          \
    if (RH4A) { h4r[iA & 3]  = h4s[(nA - 4) * CPB + lane];                   \
                p11r[iA & 3] = p11s[(nA - 4) * CPB + lane]; }                \
    if (RH4B) { h4r[iB & 3]  = h4s[(nB - 4) * CPB + lane];                   \
                p11r[iB & 3] = p11s[(nB - 4) * CPB + lane]; }                \
    if (RZA) zrb[iA & 7] = ztf[(size_t)(nA - 8) * B];                        \
    if (RZB) zrb[iB & 7] = ztf[(size_t)(nB - 8) * B];                        \
    BUILD_G(h4a, f11a, Ga00,Ga01,Ga10,Ga11, tpa,tva, Ppa00,Ppa01,Ppa11)      \
    BUILD_G(h4b, f11b, Gb00,Gb01,Gb10,Gb11, tpb,tvb, Ppb00,Ppb01,Ppb11)      \
    const float Aa0 = h4a.x - (Ga00*tpa + Ga01*tva);                         \
    const float Aa1 = h4a.y - (Ga10*tpa + Ga11*tva);                         \
    const float Ab0 = h4b.x - (Gb00*tpb + Gb01*tvb);                         \
    const float Ab1 = h4b.y - (Gb10*tpb + Gb11*tvb);                         \
    const float H00 = Gb00*Ga00 + Gb01*Ga10;                                 \
    const float H01 = Gb00*Ga01 + Gb01*Ga11;                                 \
    const float H10 = Gb10*Ga00 + Gb11*Ga10;                                 \
    const float H11 = Gb10*Ga01 + Gb11*Ga11;                                 \
    const float Bs0 = Ab0 + Gb00*Aa0 + Gb01*Aa1;                             \
    const float Bs1 = Ab1 + Gb10*Aa0 + Gb11*Aa1;                             \
    float Oa00, Oa01, Oa11, Ob00, Ob01, Ob11, Oc00, Oc01, Oc11;              \
    CONG3(Ga00,Ga01,Ga10,Ga11, Ppa00,Ppa01,Ppa11, Oa00,Oa01,Oa11)            \
    const float Ca00 = h4a.z - Oa00, Ca01 = h4a.w - Oa01;                    \
    const float Ca11 = f11a - Oa11;                                          \
    CONG3(Gb00,Gb01,Gb10,Gb11, Ppb00,Ppb01,Ppb11, Ob00,Ob01,Ob11)            \
    const float Cb00 = h4b.z - Ob00, Cb01 = h4b.w - Ob01;                    \
    const float Cb11 = f11b - Ob11;                                          \
    CONG3(Gb00,Gb01,Gb10,Gb11, Ca00,Ca01,Ca11, Oc00,Oc01,Oc11)               \
    const float C200 = Cb00 + Oc00, C201 = Cb01 + Oc01, C211 = Cb11 + Oc11;  \
    /* ---- serial apply (short chain) ---- */                               \
    const float np = Aa0 + Ga00*sp_ + Ga01*sv_;                              \
    const float t0a = Ga00*Ps00 + Ga01*Ps01;                                 \
    const float t1a = Ga00*Ps01 + Ga01*Ps11;                                 \
    const float Pn00 = Ca00 + t0a*Ga00 + t1a*Ga01;                           \
    float Ph00, Ph01, Ph11;                                                  \
    CONG3(H00,H01,H10,H11, Ps00,Ps01,Ps11, Ph00,Ph01,Ph11)                   \
    const float sm0 = Bs0 + H00*sp_ + H01*sv_;                               \
    const float sm1 = Bs1 + H10*sp_ + H11*sv_;                               \
    Ps00 = C200 + Ph00; Ps01 = C201 + Ph01; Ps11 = C211 + Ph11;              \
    sp_ = sm0; sv_ = sm1;                                                    \
    float eA = za - np;                                                      \
    const float aA = Pn00 + r;                                               \
    if (isTH) {                                                              \
      if (eA >  PI_1_5) eA -= TWO_PIc;                                       \
      if (eA < -PI_1_5) eA += TWO_PIc;                                       \
    }                                                                        \
    av[((size_t)f * T + nA) * B + seq] = aA;                                 \
    qsum += aA * eA * eA;                                                    \
    float eB = zb - sp_;                                                     \
    const float aB = Ps00 + r;                                               \
    if (isTH) {                                                              \
      if (eB >  PI_1_5) eB -= TWO_PIc;                                       \
      if (eB < -PI_1_5) eB += TWO_PIc;                                       \
    }                                                                        \
    av[((size_t)f * T + nB) * B + seq] = aB;                                 \
    qsum += aB * eB * eB;                                                    \
  }

  // pairs cover n = 126..3 (62 pairs); main j=0..55 all refills valid
  // unclamped; tail j=56..61 fully unrolled, guards fold at compile time.
#pragma unroll 4
  for (int j = 0; j < 56; j++) PAIR_BODY(2 * j, true, true, true, true)
#pragma unroll
  for (int j = 56; j < 62; j++)
    PAIR_BODY(2 * j, (122 - 2 * j) >= 0, (121 - 2 * j) >= 0,
              (118 - 2 * j) >= 0, (117 - 2 * j) >= 0)

  // ---- final single step n = 2 (i = 124) ----
  {
    const float4 h4a = h4r[124 & 3];
    const float f11a = p11r[124 & 3];
    const float za = zrb[124 & 7];
    BUILD_G(h4a, f11a, Ga00,Ga01,Ga10,Ga11, tpa,tva, Ppa00,Ppa01,Ppa11)
    const float Aa0 = h4a.x - (Ga00*tpa + Ga01*tva);
    const float np = Aa0 + Ga00*sp_ + Ga01*sv_;
    const float u0 = Ga00*Ppa00 + Ga01*Ppa01;
    const float u1 = Ga00*Ppa01 + Ga01*Ppa11;
    const float Ca00 = h4a.z - (u0*Ga00 + u1*Ga01);
    const float t0a = Ga00*Ps00 + Ga01*Ps01;
    const float t1a = Ga00*Ps01 + Ga01*Ps11;
    const float Pn00 = Ca00 + t0a*Ga00 + t1a*Ga01;
    float eA = za - np;
    const float aA = Pn00 + r;
    if (isTH) {
      if (eA >  PI_1_5) eA -= TWO_PIc;
      if (eA < -PI_1_5) eA += TWO_PIc;
    }
    av[((size_t)f * T + 2) * B + seq] = aA;
    qsum += aA * eA * eA;
  }
#undef PAIR_BODY
#undef CONG3
#undef BUILD_G

  // ---- per-wave quadratic-term reduction, one atomic per wave ----
#pragma unroll
  for (int off = 32; off > 0; off >>= 1) qsum += __shfl_down(qsum, off);
  if (lane == 0) atomicAdd(out, qsum);
}

// ---------------------------------------------------------------------------
// Reduce kernel: det term only: sum over (t,seq) of a_x*a_y*a_th.
// av layout [f][T][B] -> three coalesced float streams, float4 loads.
// ---------------------------------------------------------------------------
__global__ __launch_bounds__(RTH) void reduce_kernel(
    const float4* __restrict__ av4, float* __restrict__ out) {
  const int tid = threadIdx.x;
  constexpr int QB = B / 4;            // 1024 float4 per (f,t) row
  constexpr int NTERM4 = 126 * QB;     // t = 2..127
  float part = 0.0f;
  for (int idx = blockIdx.x * RTH + tid; idx < NTERM4; idx += RTH * RBLK) {
    const int t = 2 + (idx >> 10);     // / 1024
    const int s4 = idx & (QB - 1);
    const float4 a0 = av4[((size_t)0 * T + t) * QB + s4];
    const float4 a1 = av4[((size_t)1 * T + t) * QB + s4];
    const float4 a2 = av4[((size_t)2 * T + t) * QB + s4];
    part += a0.x * a1.x * a2.x + a0.y * a1.y * a2.y;
    part += a0.z * a1.z * a2.z + a0.w * a1.w * a2.w;
  }
#pragma unroll
  for (int off = 32; off > 0; off >>= 1) part += __shfl_down(part, off);
  __shared__ float red[RTH / 64];
  if ((tid & 63) == 0) red[tid >> 6] = part;
  __syncthreads();
  if (tid == 0) {
    float s = 0.0f;
#pragma unroll
    for (int w = 0; w < RTH / 64; w++) s += red[w];
    atomicAdd(out, s);
  }
}

}  // namespace

extern "C" void kernel_launch(void* const* d_in, const int* in_sizes, int n_in,
                              void* d_out, int out_size, void* d_ws, size_t ws_size,
                              hipStream_t stream) {
  const float* params      = (const float*)d_in[0];
  const float* covp        = (const float*)d_in[1];
  const float* init_states = (const float*)d_in[2];
  const float* z           = (const float*)d_in[3];
  float* out = (float*)d_out;

  const size_t ztB = (size_t)T * NT * sizeof(float);    // 6.3 MB
  const size_t avB = (size_t)T * NT * sizeof(float);    // 6.3 MB
  const size_t needBytes = ztB + avB;                   // 12.6 MB

  if (ws_size >= needBytes) {
    float* ztp = (float*)d_ws;
    float* avp = (float*)((char*)d_ws + ztB);
    ztrans_kernel<<<256, 256, 0, stream>>>(z, ztp, out);
    filt_kernel<<<NBLK, CPB, 0, stream>>>(params, covp, init_states, ztp,
                                          avp, out);
    reduce_kernel<<<RBLK, RTH, 0, stream>>>((const float4*)avp, out);
  } else {
    hipMemsetAsync(d_out, 0, sizeof(float), stream);
  }
}